// Round 10
// baseline (87.952 us; speedup 1.0000x reference)
//
#include <hip/hip_runtime.h>
#include <math.h>

#define BB 64
#define CC 128
#define KK 64
#define NN 4096
#define PCH 256            // pixels per chunk
#define NCH 4              // chunks per block
#define SLAB (PCH*NCH)     // 1024 pixels per block
#define NSLAB (NN/SLAB)    // 4 slabs
#define VSTRIDE ((size_t)BB*KK*CC)   // one vlad partial copy (524288 floats)

typedef __attribute__((ext_vector_type(8))) short short8;
typedef __attribute__((ext_vector_type(16))) float f32x16;

// fp32 -> bf16 bits, round-to-nearest-even
__device__ __forceinline__ unsigned f2bf(float f) {
    unsigned u = __float_as_uint(f);
    return (u + 0x7fffu + ((u >> 16) & 1u)) >> 16;
}

__device__ __forceinline__ short8 pack8(float4 a, float4 b) {
    short8 r;
    r[0]=(short)f2bf(a.x); r[1]=(short)f2bf(a.y); r[2]=(short)f2bf(a.z); r[3]=(short)f2bf(a.w);
    r[4]=(short)f2bf(b.x); r[5]=(short)f2bf(b.y); r[6]=(short)f2bf(b.z); r[7]=(short)f2bf(b.w);
    return r;
}

// LDS-only fence barrier: drains ds ops for cross-wave visibility but leaves
// global loads (vmcnt) in flight across the barrier (prefetch survives).
#define LDS_FENCE_BARRIER() do {                                  \
    asm volatile("s_waitcnt lgkmcnt(0)" ::: "memory");            \
    __builtin_amdgcn_s_barrier();                                 \
} while (0)

// ---------------- Phase 1: logits -> softmax -> vlad partials (MFMA bf16) ----
// MFMA 32x32x16 layouts (verified round 2, absmax 1.2e-4 PASS):
//   A[m][k]: lane m=l&31, k=8*(l>>5)+j ; B[k][n]: lane n=l&31, k=8*(l>>5)+j
//   C/D: col=l&31, row=(r&3)+8*(r>>2)+4*(l>>5)
// Register budget (hard-learned r6/r8/r9): (512,4)'s 128-reg cap spills this
// kernel every time; (512,2) = 256 regs is spill-free. 1 block/CU; latency
// hidden by full next-chunk prefetch (pf[16]) crossing vmcnt-preserving fences.
// This round: PCH=256, each wave computes BOTH k-tiles for its 32 pixels ->
// softmax is register-local (no redsm roundtrip); xc copy dropped (F reads x
// from global, L2-hot, overlapped with MFMA); conv_w staged in LDS.
__global__ __launch_bounds__(512, 2) void nv_phase1(
    const float* __restrict__ x,      // [B][C][N]
    const float* __restrict__ convw,  // [K][C]
    float* __restrict__ vlad,         // [B][K][C]  slab-0 partial (d_out)
    float* __restrict__ wsf)          // slabs 1..3 vlad partials + 4 asum partials
{
    __shared__ alignas(16) unsigned short xs[PCH*CC];  // 64 KB bf16 x, [n][c], swizzled
    __shared__ alignas(16) unsigned short wl[KK*CC];   // 16 KB bf16 w, [k][c], swizzled

    unsigned short* al = xs;   // a[k][n] bf16 [64][256] = 32 KB aliases xs rows 0..127:
                               // xs dead after C; al dead before next A (barriers).

    const int t  = threadIdx.x;
    const int b  = blockIdx.y;
    const int slab = blockIdx.x;
    const int n_slab = slab * SLAB;
    const int l   = t & 63;
    const int wid = t >> 6;
    const int ln  = l & 31;
    const int q   = l >> 5;
    const int ct  = wid & 3;          // vlad c-tile
    const int kt2 = wid >> 2;         // vlad k-tile
    const int r4  = t & 3;

    const float* xb = x + (size_t)b * CC * NN;
    const int n_ = ln + 32*wid;       // this wave's pixel column (0..255)
    const int c2 = ln + 32*ct;        // F: A row (channel)
    const int k2 = ln + 32*kt2;       // F: B col (cluster)

    // ---- stage conv_w -> wl[k][c] bf16, 16B-chunk swizzle ^ (k&7) ----
#pragma unroll
    for (int j = 0; j < 4; ++j) {
        int f = t * 4 + 2048 * j;     // float index, 8192 total
        float4 wv = *(const float4*)(convw + f);
        int k = f >> 7, c = f & 127;
        *(uint2*)((char*)wl + k*256 + ((((c >> 3) ^ (k & 7)) << 4) | ((c & 7) * 2)))
            = make_uint2(f2bf(wv.x) | (f2bf(wv.y) << 16), f2bf(wv.z) | (f2bf(wv.w) << 16));
    }

    // ---- prologue: chunk-0 staging loads held raw in regs ----
    float4 pf[16];
#pragma unroll
    for (int i = 0; i < 16; ++i) {
        int u = (t >> 2) + 128 * i, nQ = u & 63, cQ = u >> 6;
        pf[i] = *(const float4*)(xb + (size_t)(4*cQ + r4) * NN + n_slab + 4*nQ);
    }

    f32x16 vacc;
#pragma unroll
    for (int i = 0; i < 16; ++i) vacc[i] = 0.f;
    float asacc = 0.f;

#pragma unroll 1
    for (int chk = 0; chk < NCH; ++chk) {
        const int gn0 = n_slab + chk * PCH;
        // ---- A: cvt pf -> bf16, quad 4x4 shuffle transpose, write xs[n][c] ----
#pragma unroll
        for (int i = 0; i < 16; ++i) {
            int u = (t >> 2) + 128 * i, nQ = u & 63, cQ = u >> 6;
            unsigned d0 = f2bf(pf[i].x) | (f2bf(pf[i].y) << 16);
            unsigned d1 = f2bf(pf[i].z) | (f2bf(pf[i].w) << 16);
            unsigned q0 = (unsigned)__shfl_xor((int)d0, 1);
            unsigned q1 = (unsigned)__shfl_xor((int)d1, 1);
            unsigned e, f;
            if (r4 & 1) { e = (q0 >> 16) | (d0 & 0xffff0000u);
                          f = (q1 >> 16) | (d1 & 0xffff0000u); }
            else        { e = (d0 & 0xffffu) | (q0 << 16);
                          f = (d1 & 0xffffu) | (q1 << 16); }
            unsigned s2 = (unsigned)__shfl_xor((int)((r4 & 2) ? e : f), 2);
            unsigned w0 = (r4 & 2) ? s2 : e;
            unsigned w1 = (r4 & 2) ? f : s2;
            int nn  = 4*nQ + r4;
            int chp = (cQ >> 1) ^ (nn & 7);
            *(uint2*)((char*)xs + nn*256 + (chp << 4) + (cQ & 1)*8) = make_uint2(w0, w1);
        }
        // ---- B: issue next chunk's loads (hide under C/D/E/F via fences) ----
        if (chk + 1 < NCH) {
            const int gn1 = n_slab + (chk + 1) * PCH;
#pragma unroll
            for (int i = 0; i < 16; ++i) {
                int u = (t >> 2) + 128 * i, nQ = u & 63, cQ = u >> 6;
                pf[i] = *(const float4*)(xb + (size_t)(4*cQ + r4) * NN + gn1 + 4*nQ);
            }
        }
        LDS_FENCE_BARRIER();   // #1: xs (and wl on chk=0) visible

        // ---- C: logits, BOTH k-tiles for this wave's 32 pixels ----
        f32x16 lacc0, lacc1;
#pragma unroll
        for (int i = 0; i < 16; ++i) { lacc0[i] = 0.f; lacc1[i] = 0.f; }
#pragma unroll
        for (int cs = 0; cs < 8; ++cs) {
            int chx = (2*cs + q) ^ (n_ & 7);
            short8 xf = *(const short8*)((const char*)xs + n_*256 + (chx << 4));
            int chw = (2*cs + q) ^ (ln & 7);      // (ln+32)&7 == ln&7
            short8 w0 = *(const short8*)((const char*)wl + ln*256        + (chw << 4));
            short8 w1 = *(const short8*)((const char*)wl + (ln+32)*256   + (chw << 4));
            lacc0 = __builtin_amdgcn_mfma_f32_32x32x16_bf16(w0, xf, lacc0, 0, 0, 0);
            lacc1 = __builtin_amdgcn_mfma_f32_32x32x16_bf16(w1, xf, lacc1, 0, 0, 0);
        }

        // ---- D: softmax over all 64 k, register-local (no LDS roundtrip) ----
        float ssum = 0.f;
#pragma unroll
        for (int i = 0; i < 16; ++i) { float e2 = __expf(lacc0[i]); lacc0[i] = e2; ssum += e2; }
#pragma unroll
        for (int i = 0; i < 16; ++i) { float e2 = __expf(lacc1[i]); lacc1[i] = e2; ssum += e2; }
        ssum += __shfl_xor(ssum, 32);   // q-halves hold complementary k rows
        float inv = 1.0f / ssum;
        LDS_FENCE_BARRIER();   // #2: all xs reads done (al aliases xs)

        // ---- E: a -> al[k][n_], 32 scalar b16 writes, swizzle ^ (k&31) ----
#pragma unroll
        for (int i = 0; i < 16; ++i) {
            float a = lacc0[i] * inv;
            int k_ = 4*q + (i & 3) + 8*(i >> 2);
            *(unsigned short*)((char*)al + k_*512 + ((((n_ >> 3) ^ (k_ & 31)) << 4) | ((n_ & 7)*2)))
                = (unsigned short)f2bf(a);
        }
#pragma unroll
        for (int i = 0; i < 16; ++i) {
            float a = lacc1[i] * inv;
            int k_ = 32 + 4*q + (i & 3) + 8*(i >> 2);
            *(unsigned short*)((char*)al + k_*512 + ((((n_ >> 3) ^ (k_ & 31)) << 4) | ((n_ & 7)*2)))
                = (unsigned short)f2bf(a);
        }
        LDS_FENCE_BARRIER();   // #3: al ready

        // ---- F: vlad D[c][k] += X x A^T; x from global (L2-hot), a from LDS ----
        const float* xr = xb + (size_t)c2 * NN + gn0 + 8*q;
#pragma unroll
        for (int ns = 0; ns < 16; ++ns) {
            float4 u0 = *(const float4*)(xr + 16*ns);
            float4 u1 = *(const float4*)(xr + 16*ns + 4);
            short8 af = pack8(u0, u1);
            int cb = (2*ns + q) ^ (k2 & 31);
            short8 bf = *(const short8*)((const char*)al + k2*512 + (cb << 4));
            vacc = __builtin_amdgcn_mfma_f32_32x32x16_bf16(af, bf, vacc, 0, 0, 0);
            // asum[k2] partial: each lane sums its q-half of n; combined below.
#pragma unroll
            for (int e = 0; e < 8; ++e)
                asacc += __uint_as_float(((unsigned)(unsigned short)bf[e]) << 16);
        }
        LDS_FENCE_BARRIER();   // #4: al reads done; xs free for next A
    }

    // ---- epilogue: vlad partial tile -> plain float4 stores (NO atomics) ----
    {
        float* base = (slab == 0)
            ? vlad + (size_t)b * KK * CC
            : wsf + (size_t)(slab - 1) * VSTRIDE + (size_t)b * KK * CC;
        float* vb = base + (size_t)k2 * CC + 32*ct + 4*q;
#pragma unroll
        for (int g = 0; g < 4; ++g) {
            float4 o;
            o.x = vacc[4*g+0]; o.y = vacc[4*g+1]; o.z = vacc[4*g+2]; o.w = vacc[4*g+3];
            *(float4*)(vb + 8*g) = o;   // q0+q1 lanes tile the full 64B lines
        }
    }

    // ---- asum: combine q-halves; ct==0 waves hold k2 = ln + 32*kt2 ----
    asacc += __shfl_xor(asacc, 32);
    if ((wid & 3) == 0 && q == 0)
        wsf[3 * VSTRIDE + (size_t)slab * BB * KK + b * KK + k2] = asacc;
}

// ------- Phase 2: sum 4 partials + centroid subtract + intra/global L2 -------
__global__ __launch_bounds__(256) void nv_phase2(
    float* __restrict__ vlad,        // [B][K][C] in: slab-0 partial / out: result
    const float* __restrict__ wsf,   // slabs 1..3 vlad partials + 4 asum partials
    const float* __restrict__ cent)  // [K][C]
{
    __shared__ float gred[4];
    const int b    = blockIdx.x;
    const int w    = threadIdx.x >> 6;   // wave 0..3 -> 16 rows each
    const int lane = threadIdx.x & 63;
    const float* ap = wsf + 3 * VSTRIDE; // [4][B][K]

    float v[32];
    float gsum = 0.f;
#pragma unroll
    for (int r = 0; r < 16; r++) {
        int k = w * 16 + r;
        float a = 0.f;
#pragma unroll
        for (int s = 0; s < NSLAB; ++s) a += ap[(size_t)s * BB * KK + b * KK + k];
        size_t o = ((size_t)b * KK + k) * CC + lane;
        float x0 = vlad[o], x1 = vlad[o + 64];
#pragma unroll
        for (int s = 0; s < NSLAB - 1; ++s) {
            x0 += wsf[(size_t)s * VSTRIDE + o];
            x1 += wsf[(size_t)s * VSTRIDE + o + 64];
        }
        x0 -= a * cent[k * CC + lane];
        x1 -= a * cent[k * CC + lane + 64];
        float ss = x0 * x0 + x1 * x1;
#pragma unroll
        for (int m = 1; m < 64; m <<= 1) ss += __shfl_xor(ss, m, 64);
        float rn = 1.0f / fmaxf(sqrtf(ss), 1e-12f);
        v[2 * r]     = x0 * rn;
        v[2 * r + 1] = x1 * rn;
        gsum += ss * rn * rn;
    }
    if (lane == 0) gred[w] = gsum;
    __syncthreads();
    float g  = gred[0] + gred[1] + gred[2] + gred[3];
    float gs = 1.0f / fmaxf(sqrtf(g), 1e-12f);
#pragma unroll
    for (int r = 0; r < 16; r++) {
        int k = w * 16 + r;
        vlad[((size_t)b * KK + k) * CC + lane]      = v[2 * r]     * gs;
        vlad[((size_t)b * KK + k) * CC + lane + 64] = v[2 * r + 1] * gs;
    }
}

extern "C" void kernel_launch(void* const* d_in, const int* in_sizes, int n_in,
                              void* d_out, int out_size, void* d_ws, size_t ws_size,
                              hipStream_t stream) {
    const float* x     = (const float*)d_in[0];
    const float* convw = (const float*)d_in[1];
    const float* cent  = (const float*)d_in[2];
    float* out = (float*)d_out;
    float* wsf = (float*)d_ws;   // 3*VSTRIDE vlad partials + 4*B*K asum = ~6.4 MB

    nv_phase1<<<dim3(NSLAB, BB), 512, 0, stream>>>(x, convw, out, wsf);
    nv_phase2<<<BB, 256, 0, stream>>>(out, wsf, cent);
}

// Round 11
// 60.404 us; speedup vs baseline: 1.4561x; 1.4561x over previous
//
#include <hip/hip_runtime.h>
#include <math.h>

#define BB 64
#define CC 128
#define KK 64
#define NN 4096
#define PCH 128            // pixels per chunk
#define NCH 4              // chunks per block
#define SLAB (PCH*NCH)     // 512 pixels per block
#define NSLAB (NN/SLAB)    // 8 slabs
#define VSTRIDE ((size_t)BB*KK*CC)   // one vlad partial copy (524288 floats)

typedef __attribute__((ext_vector_type(8))) short short8;
typedef __attribute__((ext_vector_type(16))) float f32x16;

// fp32 -> bf16 bits, round-to-nearest-even
__device__ __forceinline__ unsigned f2bf(float f) {
    unsigned u = __float_as_uint(f);
    return (u + 0x7fffu + ((u >> 16) & 1u)) >> 16;
}

__device__ __forceinline__ short8 pack8(float4 a, float4 b) {
    short8 r;
    r[0]=(short)f2bf(a.x); r[1]=(short)f2bf(a.y); r[2]=(short)f2bf(a.z); r[3]=(short)f2bf(a.w);
    r[4]=(short)f2bf(b.x); r[5]=(short)f2bf(b.y); r[6]=(short)f2bf(b.z); r[7]=(short)f2bf(b.w);
    return r;
}

// LDS-only fence barrier: drains ds ops for cross-wave visibility but leaves
// global loads (vmcnt) in flight across the barrier.
#define LDS_FENCE_BARRIER() do {                                  \
    asm volatile("s_waitcnt lgkmcnt(0)" ::: "memory");            \
    __builtin_amdgcn_s_barrier();                                 \
} while (0)

// ---------------- Phase 1: logits -> softmax -> vlad partials (MFMA bf16) ----
// MFMA 32x32x16 layouts (verified round 2, absmax 1.2e-4 PASS):
//   A[m][k]: lane m=l&31, k=8*(l>>5)+j ; B[k][n]: lane n=l&31, k=8*(l>>5)+j
//   C/D: col=l&31, row=(r&3)+8*(r>>2)+4*(l>>5)
// LDS 16B-chunk XOR swizzle: chunk' = chunk ^ (row & 7)
// Scoreboard lessons baked in:
//   - r2/r8/r9: 128-reg cap spills this kernel -> need 256-reg budget.
//   - r2/r10: F reading x from global regresses 2x -> both operands from LDS.
//   - r7 champion (48.9us) = 1x512-thread block/CU, single barrier domain.
//   - THIS ROUND: 2x256-thread blocks/CU = two independent barrier domains
//     at the same 256-reg budget; each wave computes BOTH k-tiles so softmax
//     is register-local (4 waves can't cross-wave-pair like 8 could).
__global__ __launch_bounds__(256, 2) void nv_phase1(
    const float* __restrict__ x,      // [B][C][N]
    const float* __restrict__ convw,  // [K][C]
    float* __restrict__ vlad,         // [B][K][C]  slab-0 partial (d_out)
    float* __restrict__ wsf)          // slabs 1..7 vlad partials + 8 asum partials
{
    __shared__ alignas(16) unsigned short xs[PCH*CC];  // 32 KB bf16 x, [n][c], swizzled
    __shared__ alignas(16) unsigned short xc[CC*PCH];  // 32 KB bf16 x, [c][n], swizzled

    unsigned short* al = xs;   // a[k][n] bf16 [64][128] = 16 KB aliases xs rows 0..63:
                               // xs dead after C (barrier #2); al dead before next A.

    const int t  = threadIdx.x;
    const int b  = blockIdx.y;
    const int slab = blockIdx.x;
    const int n_slab = slab * SLAB;
    const int l   = t & 63;
    const int wid = t >> 6;           // wave 0..3
    const int ln  = l & 31;
    const int q   = l >> 5;
    const int r4  = t & 3;

    const float* xb = x + (size_t)b * CC * NN;
    const int n_ = ln + 32*wid;       // this wave's pixel (chunk-local, 0..127)
    const int c2 = ln + 32*wid;       // F: A row (channel), c-tile = wid

    // ---- preload conv_w fragments for BOTH k-tiles (reused all chunks) ----
    short8 wfrag0[8], wfrag1[8];
    {
        const float* wr0 = convw + (size_t)ln * CC + 8*q;
        const float* wr1 = convw + (size_t)(ln + 32) * CC + 8*q;
#pragma unroll
        for (int cs = 0; cs < 8; ++cs) {
            wfrag0[cs] = pack8(*(const float4*)(wr0 + 16*cs), *(const float4*)(wr0 + 16*cs + 4));
            wfrag1[cs] = pack8(*(const float4*)(wr1 + 16*cs), *(const float4*)(wr1 + 16*cs + 4));
        }
    }

    f32x16 vacc0, vacc1;
#pragma unroll
    for (int i = 0; i < 16; ++i) { vacc0[i] = 0.f; vacc1[i] = 0.f; }
    float asacc0 = 0.f, asacc1 = 0.f;

#pragma unroll 1
    for (int chk = 0; chk < NCH; ++chk) {
        const int gn0 = n_slab + chk * PCH;
        // ---- A: load x chunk (16 float4/thread in flight), cvt, write xs+xc ----
        {
            float4 v[16];
#pragma unroll
            for (int i = 0; i < 16; ++i) {
                int u = (t >> 2) + 64 * i, cQ = u >> 5, nQ = u & 31;
                v[i] = *(const float4*)(xb + (size_t)(4*cQ + r4) * NN + gn0 + 4*nQ);
            }
#pragma unroll
            for (int i = 0; i < 16; ++i) {
                int u = (t >> 2) + 64 * i, cQ = u >> 5, nQ = u & 31;
                unsigned d0 = f2bf(v[i].x) | (f2bf(v[i].y) << 16);
                unsigned d1 = f2bf(v[i].z) | (f2bf(v[i].w) << 16);
                // xc: straight write, 4 consecutive n at row c
                int c = 4*cQ + r4;
                *(uint2*)((char*)xc + c*256 + ((((nQ >> 1) ^ (c & 7)) << 4) | ((nQ & 1) * 8)))
                    = make_uint2(d0, d1);
                // xs: quad 4x4 shuffle transpose (verified round 2)
                unsigned q0 = (unsigned)__shfl_xor((int)d0, 1);
                unsigned q1 = (unsigned)__shfl_xor((int)d1, 1);
                unsigned e, f;
                if (r4 & 1) { e = (q0 >> 16) | (d0 & 0xffff0000u);
                              f = (q1 >> 16) | (d1 & 0xffff0000u); }
                else        { e = (d0 & 0xffffu) | (q0 << 16);
                              f = (d1 & 0xffffu) | (q1 << 16); }
                unsigned s2 = (unsigned)__shfl_xor((int)((r4 & 2) ? e : f), 2);
                unsigned w0 = (r4 & 2) ? s2 : e;
                unsigned w1 = (r4 & 2) ? f : s2;
                int nn  = 4*nQ + r4;
                int chp = (cQ >> 1) ^ (nn & 7);
                *(uint2*)((char*)xs + nn*256 + (chp << 4) + (cQ & 1)*8) = make_uint2(w0, w1);
            }
        }
        LDS_FENCE_BARRIER();   // #1: xs, xc visible

        // ---- C: logits, BOTH k-tiles for this wave's 32 pixels ----
        f32x16 lacc0, lacc1;
#pragma unroll
        for (int i = 0; i < 16; ++i) { lacc0[i] = 0.f; lacc1[i] = 0.f; }
#pragma unroll
        for (int cs = 0; cs < 8; ++cs) {
            int chx = (2*cs + q) ^ (n_ & 7);
            short8 xf = *(const short8*)((const char*)xs + n_*256 + (chx << 4));
            lacc0 = __builtin_amdgcn_mfma_f32_32x32x16_bf16(wfrag0[cs], xf, lacc0, 0, 0, 0);
            lacc1 = __builtin_amdgcn_mfma_f32_32x32x16_bf16(wfrag1[cs], xf, lacc1, 0, 0, 0);
        }

        // ---- D: softmax over all 64 k, register-local (no LDS roundtrip) ----
        float ssum = 0.f;
#pragma unroll
        for (int i = 0; i < 16; ++i) { float e2 = __expf(lacc0[i]); lacc0[i] = e2; ssum += e2; }
#pragma unroll
        for (int i = 0; i < 16; ++i) { float e2 = __expf(lacc1[i]); lacc1[i] = e2; ssum += e2; }
        ssum += __shfl_xor(ssum, 32);   // q-halves hold complementary k rows
        float inv = 1.0f / ssum;
        LDS_FENCE_BARRIER();   // #2: all xs reads done (al aliases xs)

        // ---- E: a -> al[k][n_], 32 scalar b16 writes, swizzle ^ (k&7) ----
#pragma unroll
        for (int i = 0; i < 16; ++i) {
            float a = lacc0[i] * inv;
            int k_ = 4*q + (i & 3) + 8*(i >> 2);
            al[k_*128 + ((((n_ >> 3) ^ (k_ & 7)) << 3) | (n_ & 7))] = (unsigned short)f2bf(a);
        }
#pragma unroll
        for (int i = 0; i < 16; ++i) {
            float a = lacc1[i] * inv;
            int k_ = 32 + 4*q + (i & 3) + 8*(i >> 2);
            al[k_*128 + ((((n_ >> 3) ^ (k_ & 7)) << 3) | (n_ & 7))] = (unsigned short)f2bf(a);
        }
        LDS_FENCE_BARRIER();   // #3: al ready

        // ---- F: vlad, BOTH k-tiles for this wave's c-tile; all from LDS ----
#pragma unroll
        for (int ns = 0; ns < 8; ++ns) {
            int ca = (2*ns + q) ^ (c2 & 7);
            short8 af = *(const short8*)((const char*)xc + c2*256 + (ca << 4));
            int cb = (2*ns + q) ^ (ln & 7);    // (ln+32)&7 == ln&7
            short8 bf0 = *(const short8*)((const char*)al + ln*256        + (cb << 4));
            short8 bf1 = *(const short8*)((const char*)al + (ln + 32)*256 + (cb << 4));
            vacc0 = __builtin_amdgcn_mfma_f32_32x32x16_bf16(af, bf0, vacc0, 0, 0, 0);
            vacc1 = __builtin_amdgcn_mfma_f32_32x32x16_bf16(af, bf1, vacc1, 0, 0, 0);
            if (wid == 0) {   // asum: all waves read identical al rows; one counts
#pragma unroll
                for (int e = 0; e < 8; ++e) {
                    asacc0 += __uint_as_float(((unsigned)(unsigned short)bf0[e]) << 16);
                    asacc1 += __uint_as_float(((unsigned)(unsigned short)bf1[e]) << 16);
                }
            }
        }
        LDS_FENCE_BARRIER();   // #4: al/xc reads done; LDS free for next A
    }

    // ---- epilogue: vlad partial tile -> plain float4 stores (NO atomics) ----
    {
        float* base = (slab == 0)
            ? vlad + (size_t)b * KK * CC
            : wsf + (size_t)(slab - 1) * VSTRIDE + (size_t)b * KK * CC;
        float* vb0 = base + (size_t)ln * CC        + 32*wid + 4*q;
        float* vb1 = base + (size_t)(ln + 32) * CC + 32*wid + 4*q;
#pragma unroll
        for (int g = 0; g < 4; ++g) {
            float4 o0, o1;
            o0.x = vacc0[4*g+0]; o0.y = vacc0[4*g+1]; o0.z = vacc0[4*g+2]; o0.w = vacc0[4*g+3];
            o1.x = vacc1[4*g+0]; o1.y = vacc1[4*g+1]; o1.z = vacc1[4*g+2]; o1.w = vacc1[4*g+3];
            *(float4*)(vb0 + 8*g) = o0;
            *(float4*)(vb1 + 8*g) = o1;
        }
    }

    // ---- asum: combine q-halves in wave 0, plain stores ----
    if (wid == 0) {
        asacc0 += __shfl_xor(asacc0, 32);
        asacc1 += __shfl_xor(asacc1, 32);
        if (q == 0) {
            float* ab = wsf + 7 * VSTRIDE + (size_t)slab * BB * KK + (size_t)b * KK;
            ab[ln]      = asacc0;
            ab[ln + 32] = asacc1;
        }
    }
}

// ------- Phase 2: sum 8 partials + centroid subtract + intra/global L2 -------
__global__ __launch_bounds__(256) void nv_phase2(
    float* __restrict__ vlad,        // [B][K][C] in: slab-0 partial / out: result
    const float* __restrict__ wsf,   // slabs 1..7 vlad partials + 8 asum partials
    const float* __restrict__ cent)  // [K][C]
{
    __shared__ float gred[4];
    const int b    = blockIdx.x;
    const int w    = threadIdx.x >> 6;   // wave 0..3 -> 16 rows each
    const int lane = threadIdx.x & 63;
    const float* ap = wsf + 7 * VSTRIDE; // [8][B][K]

    float v[32];
    float gsum = 0.f;
#pragma unroll
    for (int r = 0; r < 16; r++) {
        int k = w * 16 + r;
        float a = 0.f;
#pragma unroll
        for (int s = 0; s < NSLAB; ++s) a += ap[(size_t)s * BB * KK + b * KK + k];
        size_t o = ((size_t)b * KK + k) * CC + lane;
        float x0 = vlad[o], x1 = vlad[o + 64];
#pragma unroll
        for (int s = 0; s < NSLAB - 1; ++s) {
            x0 += wsf[(size_t)s * VSTRIDE + o];
            x1 += wsf[(size_t)s * VSTRIDE + o + 64];
        }
        x0 -= a * cent[k * CC + lane];
        x1 -= a * cent[k * CC + lane + 64];
        float ss = x0 * x0 + x1 * x1;
#pragma unroll
        for (int m = 1; m < 64; m <<= 1) ss += __shfl_xor(ss, m, 64);
        float rn = 1.0f / fmaxf(sqrtf(ss), 1e-12f);
        v[2 * r]     = x0 * rn;
        v[2 * r + 1] = x1 * rn;
        gsum += ss * rn * rn;
    }
    if (lane == 0) gred[w] = gsum;
    __syncthreads();
    float g  = gred[0] + gred[1] + gred[2] + gred[3];
    float gs = 1.0f / fmaxf(sqrtf(g), 1e-12f);
#pragma unroll
    for (int r = 0; r < 16; r++) {
        int k = w * 16 + r;
        vlad[((size_t)b * KK + k) * CC + lane]      = v[2 * r]     * gs;
        vlad[((size_t)b * KK + k) * CC + lane + 64] = v[2 * r + 1] * gs;
    }
}

extern "C" void kernel_launch(void* const* d_in, const int* in_sizes, int n_in,
                              void* d_out, int out_size, void* d_ws, size_t ws_size,
                              hipStream_t stream) {
    const float* x     = (const float*)d_in[0];
    const float* convw = (const float*)d_in[1];
    const float* cent  = (const float*)d_in[2];
    float* out = (float*)d_out;
    float* wsf = (float*)d_ws;   // 7*VSTRIDE vlad partials + 8*B*K asum = ~14.8 MB

    nv_phase1<<<dim3(NSLAB, BB), 256, 0, stream>>>(x, convw, out, wsf);
    nv_phase2<<<BB, 256, 0, stream>>>(out, wsf, cent);
}